// Round 7
// baseline (3016.347 us; speedup 1.0000x reference)
//
#include <hip/hip_runtime.h>
#include <stdint.h>
#include <math.h>

#define NN 50000
#define NE 800000

typedef __attribute__((ext_vector_type(8))) __bf16 bf16x8;
typedef __attribute__((ext_vector_type(8))) unsigned short u16x8;
typedef __attribute__((ext_vector_type(4))) float f32x4;
typedef unsigned int uint32;

// ---------------------------------------------------------------------------
// One-time CSR build: histogram -> exclusive scan -> scatter (src only).
// ---------------------------------------------------------------------------
__global__ void hist_k(const int* __restrict__ dst, int* __restrict__ hist) {
    int e = blockIdx.x * 256 + threadIdx.x;
    if (e < NE) atomicAdd(&hist[dst[e]], 1);
}

__global__ void scan_k(const int* __restrict__ hist, int* __restrict__ row_off) {
    __shared__ int lds[1024];
    const int tid = threadIdx.x;
    int carry = 0;
    for (int base = 0; base < NN; base += 1024) {
        int i = base + tid;
        int v = (i < NN) ? hist[i] : 0;
        lds[tid] = v;
        __syncthreads();
        #pragma unroll
        for (int s = 1; s < 1024; s <<= 1) {
            int add = (tid >= s) ? lds[tid - s] : 0;
            __syncthreads();
            lds[tid] += add;
            __syncthreads();
        }
        int incl = lds[tid];
        if (i < NN) row_off[i] = carry + incl - v;   // exclusive
        carry += lds[1023];
        __syncthreads();
    }
    if (tid == 0) row_off[NN] = carry;               // == NE
}

__global__ void copy_k(const int* __restrict__ a, int* __restrict__ b, int n) {
    int i = blockIdx.x * 256 + threadIdx.x;
    if (i < n) b[i] = a[i];
}

__global__ void scatter_k(const int* __restrict__ src, const int* __restrict__ dst,
                          int* __restrict__ cnt, int* __restrict__ s_src) {
    int e = blockIdx.x * 256 + threadIdx.x;
    if (e < NE) {
        int d = dst[e];
        int p = atomicAdd(&cnt[d], 1);
        s_src[p] = src[e];
    }
}

// ---------------------------------------------------------------------------
// Node transform: u = y @ (W1a - W1b) + b1 ; v = y @ W1b   (fp32 VALU)
// ---------------------------------------------------------------------------
template<int CIN, int COUT, bool FIRST>
__global__ void node_transform(const float* __restrict__ xin,
                               const float* __restrict__ ain,
                               const float* __restrict__ b2p,
                               const float* __restrict__ W1,
                               const float* __restrict__ b1,
                               float* __restrict__ U,
                               float* __restrict__ Vv)
{
    __shared__ float ylds[32][CIN];
    const int nbase = blockIdx.x * 32;
    const int tid = threadIdx.x;

    for (int idx = tid; idx < 32 * CIN; idx += COUT) {
        int nn = idx / CIN, k = idx - nn * CIN;
        int n = nbase + nn;
        float val = 0.f;
        if (n < NN) {
            if (FIRST) {
                val = xin[(size_t)n * CIN + k];
            } else {
                float a = ain[(size_t)n * CIN + k];
                val = fmaxf(a + b2p[k], 0.f);   // -inf sentinel -> 0
            }
        }
        ylds[nn][k] = val;
    }
    __syncthreads();

    const int j = tid;
    float ua[32], va[32];
    #pragma unroll
    for (int t = 0; t < 32; ++t) { ua[t] = 0.f; va[t] = 0.f; }

    for (int k4 = 0; k4 < CIN / 4; ++k4) {
        float wd[4], wb[4];
        #pragma unroll
        for (int i = 0; i < 4; ++i) {
            float a = W1[(size_t)(k4 * 4 + i) * COUT + j];
            float b = W1[(size_t)(CIN + k4 * 4 + i) * COUT + j];
            wb[i] = b;
            wd[i] = a - b;
        }
        #pragma unroll
        for (int t = 0; t < 32; ++t) {
            const float4 y4 = *reinterpret_cast<const float4*>(&ylds[t][k4 * 4]);
            ua[t] = fmaf(y4.x, wd[0], ua[t]);
            ua[t] = fmaf(y4.y, wd[1], ua[t]);
            ua[t] = fmaf(y4.z, wd[2], ua[t]);
            ua[t] = fmaf(y4.w, wd[3], ua[t]);
            va[t] = fmaf(y4.x, wb[0], va[t]);
            va[t] = fmaf(y4.y, wb[1], va[t]);
            va[t] = fmaf(y4.z, wb[2], va[t]);
            va[t] = fmaf(y4.w, wb[3], va[t]);
        }
    }

    const float bj = b1[j];
    for (int t = 0; t < 32; ++t) {
        int n = nbase + t;
        if (n < NN) {
            U [(size_t)n * COUT + j] = ua[t] + bj;
            Vv[(size_t)n * COUT + j] = va[t];
        }
    }
}

// ---------------------------------------------------------------------------
// W2 -> MFMA B-fragment prep (hi/lo bf16 split), fragment-packed layout.
// frag = nt*KS + ks; lane l holds W2[ks*32 + (l>>4)*8 + m][nt*16 + (l&15)],
// m=0..7, packed as 8 ushort at F[(frag*64+lane)*8].  (HW-verified rounds 4-6.)
// ---------------------------------------------------------------------------
template<int COUT>
__global__ void w2frag_prep(const float* __restrict__ W2,
                            unsigned short* __restrict__ Fhi,
                            unsigned short* __restrict__ Flo)
{
    constexpr int KS = COUT / 32;
    constexpr int NT = COUT / 16;
    int t = blockIdx.x * 256 + threadIdx.x;
    if (t >= NT * KS * 64) return;
    int frag = t >> 6, lane = t & 63;
    int ks = frag % KS, nt = frag / KS;
    int col = nt * 16 + (lane & 15);
    int k0 = ks * 32 + (lane >> 4) * 8;
    unsigned short h8[8], l8[8];
    #pragma unroll
    for (int m = 0; m < 8; ++m) {
        float w = W2[(size_t)(k0 + m) * COUT + col];
        __bf16 hb = (__bf16)w;
        float hf = (float)hb;
        __bf16 lb = (__bf16)(w - hf);
        h8[m] = __builtin_bit_cast(unsigned short, hb);
        l8[m] = __builtin_bit_cast(unsigned short, lb);
    }
    size_t base = (size_t)t * 8;
    #pragma unroll
    for (int m = 0; m < 8; ++m) { Fhi[base + m] = h8[m]; Flo[base + m] = l8[m]; }
}

// ---------------------------------------------------------------------------
// MFMA edge kernel, direct-gather A, SINGLE-pass 16-edge tiles.
// Round-7 spill fix: arch-VGPR live set minimized -- U row moved to LDS
// (16-lane broadcast reads, ~free), one acc set (32 regs), one split
// pipeline, V loaded per-ks (8 transient regs). B hi+lo streamed from LDS
// (frag-packed, lane-contiguous b128, conflict-free; proven rounds 4-6).
// 512 thr = 8 nodes/block; (512,2): 256-reg unified budget, live ~130.
// ---------------------------------------------------------------------------
static __device__ __forceinline__ void split8(const float* t, bf16x8& hi, bf16x8& lo) {
    u16x8 h, l;
    #pragma unroll
    for (int i = 0; i < 8; ++i) {
        __bf16 hb = (__bf16)t[i];
        float hf = (float)hb;
        __bf16 lb = (__bf16)(t[i] - hf);
        h[i] = __builtin_bit_cast(unsigned short, hb);
        l[i] = __builtin_bit_cast(unsigned short, lb);
    }
    hi = __builtin_bit_cast(bf16x8, h);
    lo = __builtin_bit_cast(bf16x8, l);
}

template<int COUT>
__global__ void __launch_bounds__(512, 2) edge_node_mfma(
    const float* __restrict__ U, const float* __restrict__ Vv,
    const int* __restrict__ s_src, const int* __restrict__ row_off,
    const unsigned short* __restrict__ Fhi, const unsigned short* __restrict__ Flo,
    float* __restrict__ agg)
{
    constexpr int KS = COUT / 32;          // MFMA K-steps (4 / 2)
    constexpr int NT = COUT / 16;          // output col tiles (8 / 4)
    constexpr int NFRAG = KS * NT;

    __shared__ __align__(16) unsigned short w2hi[NFRAG * 512];
    __shared__ __align__(16) unsigned short w2lo[NFRAG * 512];
    __shared__ __align__(16) float u_lds[8 * COUT];

    const int tid = threadIdx.x;
    for (int i = tid; i < NFRAG * 64; i += 512) {
        *reinterpret_cast<u16x8*>(&w2hi[i * 8]) =
            *reinterpret_cast<const u16x8*>(&Fhi[(size_t)i * 8]);
        *reinterpret_cast<u16x8*>(&w2lo[i * 8]) =
            *reinterpret_cast<const u16x8*>(&Flo[(size_t)i * 8]);
    }

    const int wave = tid >> 6, lane = tid & 63;
    const int arow = lane & 15;            // A row (edge within pass)
    const int akc  = lane >> 4;            // k-chunk within K-step

    const int n = blockIdx.x * 8 + wave;   // grid = NN/8 exactly
    const int off0 = row_off[n];
    const int deg  = row_off[n + 1] - off0;

    // stage this wave's U row to LDS
    for (int i = lane; i < COUT; i += 64)
        u_lds[wave * COUT + i] = U[(size_t)n * COUT + i];

    __syncthreads();   // w2 + U ready; no block syncs after this

    float nmax[NT];
    #pragma unroll
    for (int nt = 0; nt < NT; ++nt) nmax[nt] = -INFINITY;

    for (int pb = 0; pb < deg; pb += 16) {
        const bool valid = (pb + arow) < deg;
        const int sv = valid ? s_src[off0 + pb + arow] : 0;
        const float* vrow = &Vv[(size_t)sv * COUT];
        const float vm = valid ? 1.f : 0.f;

        f32x4 acc[NT];
        #pragma unroll
        for (int nt = 0; nt < NT; ++nt) acc[nt] = f32x4{0.f, 0.f, 0.f, 0.f};

        #pragma unroll
        for (int ks = 0; ks < KS; ++ks) {
            const int kof = (ks * 4 + akc) * 8;
            // U chunk: broadcast LDS read (16 lanes same addr)
            const float4 ua = *reinterpret_cast<const float4*>(&u_lds[wave * COUT + kof]);
            const float4 ub = *reinterpret_cast<const float4*>(&u_lds[wave * COUT + kof + 4]);
            const float4 va = *reinterpret_cast<const float4*>(vrow + kof);
            const float4 vb = *reinterpret_cast<const float4*>(vrow + kof + 4);

            float t8[8];
            t8[0] = vm * fmaxf(ua.x + va.x, 0.f);
            t8[1] = vm * fmaxf(ua.y + va.y, 0.f);
            t8[2] = vm * fmaxf(ua.z + va.z, 0.f);
            t8[3] = vm * fmaxf(ua.w + va.w, 0.f);
            t8[4] = vm * fmaxf(ub.x + vb.x, 0.f);
            t8[5] = vm * fmaxf(ub.y + vb.y, 0.f);
            t8[6] = vm * fmaxf(ub.z + vb.z, 0.f);
            t8[7] = vm * fmaxf(ub.w + vb.w, 0.f);
            bf16x8 ahi, alo;
            split8(t8, ahi, alo);

            #pragma unroll
            for (int nt = 0; nt < NT; ++nt) {
                const size_t fb = (size_t)((nt * KS + ks) * 64 + lane) * 8;
                bf16x8 bhi = __builtin_bit_cast(bf16x8,
                    *reinterpret_cast<const u16x8*>(&w2hi[fb]));
                bf16x8 blo = __builtin_bit_cast(bf16x8,
                    *reinterpret_cast<const u16x8*>(&w2lo[fb]));
                acc[nt] = __builtin_amdgcn_mfma_f32_16x16x32_bf16(ahi, bhi, acc[nt], 0, 0, 0);
                acc[nt] = __builtin_amdgcn_mfma_f32_16x16x32_bf16(ahi, blo, acc[nt], 0, 0, 0);
                acc[nt] = __builtin_amdgcn_mfma_f32_16x16x32_bf16(alo, bhi, acc[nt], 0, 0, 0);
            }
        }

        // masked max (D: row = akc*4 + r, col = nt*16 + (lane&15))
        #pragma unroll
        for (int nt = 0; nt < NT; ++nt) {
            float m4 = -INFINITY;
            #pragma unroll
            for (int r = 0; r < 4; ++r) {
                int e = akc * 4 + r;
                if (pb + e < deg) m4 = fmaxf(m4, acc[nt][r]);
            }
            m4 = fmaxf(m4, __shfl_xor(m4, 16, 64));
            m4 = fmaxf(m4, __shfl_xor(m4, 32, 64));
            nmax[nt] = fmaxf(nmax[nt], m4);
        }
    }

    // direct store; deg==0 leaves -inf sentinel
    if (lane < 16) {
        #pragma unroll
        for (int nt = 0; nt < NT; ++nt)
            agg[(size_t)n * COUT + nt * 16 + lane] = nmax[nt];
    }
}

__global__ void finalize_k(const float* __restrict__ agg,
                           const float* __restrict__ b2,
                           float* __restrict__ out) {
    int i = blockIdx.x * 256 + threadIdx.x;
    if (i < NN * 128) {
        float a = agg[i];
        out[i] = (a == -INFINITY) ? 0.f : a + b2[i & 127];
    }
}

// ---------------------------------------------------------------------------
extern "C" void kernel_launch(void* const* d_in, const int* in_sizes, int n_in,
                              void* d_out, int out_size, void* d_ws, size_t ws_size,
                              hipStream_t stream)
{
    const float* x  = (const float*)d_in[0];
    const int*   ei = (const int*)d_in[1];
    const int* src = ei;          // edge_index[0]
    const int* dst = ei + NE;     // edge_index[1]

    const float *W1[4], *B1[4], *W2[4], *B2[4];
    for (int i = 0; i < 4; ++i) {
        W1[i] = (const float*)d_in[2 + 4 * i];
        B1[i] = (const float*)d_in[3 + 4 * i];
        W2[i] = (const float*)d_in[4 + 4 * i];
        B2[i] = (const float*)d_in[5 + 4 * i];
    }

    float* U   = (float*)d_ws;
    float* V   = U   + (size_t)NN * 128;
    float* agg = V   + (size_t)NN * 128;
    int* row_off = (int*)(agg + (size_t)NN * 128);   // NN+16 ints (padded)
    int* cnt     = row_off + (NN + 16);              // NN+16 ints
    int* s_src   = cnt + (NN + 16);                  // NE ints
    unsigned short* fbase = (unsigned short*)(s_src + NE);
    unsigned short *FH[4], *FL[4];
    for (int i = 0; i < 4; ++i) {
        FH[i] = fbase + (size_t)i * 32768;
        FL[i] = FH[i] + 16384;
    }

    float* out = (float*)d_out;

    // ---- one-time CSR build ----
    (void)hipMemsetAsync(cnt, 0, (size_t)NN * sizeof(int), stream);
    hipLaunchKernelGGL(hist_k, dim3((NE + 255) / 256), dim3(256), 0, stream, dst, cnt);
    hipLaunchKernelGGL(scan_k, dim3(1), dim3(1024), 0, stream, cnt, row_off);
    hipLaunchKernelGGL(copy_k, dim3((NN + 255) / 256), dim3(256), 0, stream, row_off, cnt, NN);
    hipLaunchKernelGGL(scatter_k, dim3((NE + 255) / 256), dim3(256), 0, stream, src, dst, cnt, s_src);

    // ---- W2 fragment prep (hi/lo bf16 split), all 4 layers ----
    hipLaunchKernelGGL((w2frag_prep<64>),  dim3(2), dim3(256), 0, stream, W2[0], FH[0], FL[0]);
    hipLaunchKernelGGL((w2frag_prep<128>), dim3(8), dim3(256), 0, stream, W2[1], FH[1], FL[1]);
    hipLaunchKernelGGL((w2frag_prep<128>), dim3(8), dim3(256), 0, stream, W2[2], FH[2], FL[2]);
    hipLaunchKernelGGL((w2frag_prep<128>), dim3(8), dim3(256), 0, stream, W2[3], FH[3], FL[3]);

    const int nblkA = (NN + 31) / 32;
    const int nblkE = NN / 8;      // 6250

    // ---- layer 0: 32 -> 64 ----
    hipLaunchKernelGGL((node_transform<32, 64, true>), dim3(nblkA), dim3(64), 0, stream,
                       x, nullptr, nullptr, W1[0], B1[0], U, V);
    hipLaunchKernelGGL((edge_node_mfma<64>), dim3(nblkE), dim3(512), 0, stream,
                       U, V, s_src, row_off, FH[0], FL[0], agg);

    // ---- layer 1: 64 -> 128 ----
    hipLaunchKernelGGL((node_transform<64, 128, false>), dim3(nblkA), dim3(128), 0, stream,
                       nullptr, agg, B2[0], W1[1], B1[1], U, V);
    hipLaunchKernelGGL((edge_node_mfma<128>), dim3(nblkE), dim3(512), 0, stream,
                       U, V, s_src, row_off, FH[1], FL[1], agg);

    // ---- layer 2: 128 -> 128 ----
    hipLaunchKernelGGL((node_transform<128, 128, false>), dim3(nblkA), dim3(128), 0, stream,
                       nullptr, agg, B2[1], W1[2], B1[2], U, V);
    hipLaunchKernelGGL((edge_node_mfma<128>), dim3(nblkE), dim3(512), 0, stream,
                       U, V, s_src, row_off, FH[2], FL[2], agg);

    // ---- layer 3: 128 -> 128 ----
    hipLaunchKernelGGL((node_transform<128, 128, false>), dim3(nblkA), dim3(128), 0, stream,
                       nullptr, agg, B2[2], W1[3], B1[3], U, V);
    hipLaunchKernelGGL((edge_node_mfma<128>), dim3(nblkE), dim3(512), 0, stream,
                       U, V, s_src, row_off, FH[3], FL[3], agg);

    // ---- finalize: +b2_3, empty -> 0 ----
    hipLaunchKernelGGL(finalize_k, dim3((NN * 128 + 255) / 256), dim3(256), 0, stream,
                       agg, B2[3], out);
}

// Round 8
// 1055.374 us; speedup vs baseline: 2.8581x; 2.8581x over previous
//
#include <hip/hip_runtime.h>
#include <stdint.h>
#include <math.h>

#define NN 50000
#define NE 800000

typedef __attribute__((ext_vector_type(8))) __bf16 bf16x8;
typedef __attribute__((ext_vector_type(8))) unsigned short u16x8;
typedef __attribute__((ext_vector_type(4))) float f32x4;

// ---------------------------------------------------------------------------
// One-time CSR build: histogram -> exclusive scan -> scatter (src only).
// ---------------------------------------------------------------------------
__global__ void hist_k(const int* __restrict__ dst, int* __restrict__ hist) {
    int e = blockIdx.x * 256 + threadIdx.x;
    if (e < NE) atomicAdd(&hist[dst[e]], 1);
}

__global__ void scan_k(const int* __restrict__ hist, int* __restrict__ row_off) {
    __shared__ int lds[1024];
    const int tid = threadIdx.x;
    int carry = 0;
    for (int base = 0; base < NN; base += 1024) {
        int i = base + tid;
        int v = (i < NN) ? hist[i] : 0;
        lds[tid] = v;
        __syncthreads();
        #pragma unroll
        for (int s = 1; s < 1024; s <<= 1) {
            int add = (tid >= s) ? lds[tid - s] : 0;
            __syncthreads();
            lds[tid] += add;
            __syncthreads();
        }
        int incl = lds[tid];
        if (i < NN) row_off[i] = carry + incl - v;   // exclusive
        carry += lds[1023];
        __syncthreads();
    }
    if (tid == 0) row_off[NN] = carry;               // == NE
}

__global__ void copy_k(const int* __restrict__ a, int* __restrict__ b, int n) {
    int i = blockIdx.x * 256 + threadIdx.x;
    if (i < n) b[i] = a[i];
}

__global__ void scatter_k(const int* __restrict__ src, const int* __restrict__ dst,
                          int* __restrict__ cnt, int* __restrict__ s_src) {
    int e = blockIdx.x * 256 + threadIdx.x;
    if (e < NE) {
        int d = dst[e];
        int p = atomicAdd(&cnt[d], 1);
        s_src[p] = src[e];
    }
}

// ---------------------------------------------------------------------------
// Node transform: u = y @ (W1a - W1b) + b1 ; v = y @ W1b   (fp32 VALU)
// ---------------------------------------------------------------------------
template<int CIN, int COUT, bool FIRST>
__global__ void node_transform(const float* __restrict__ xin,
                               const float* __restrict__ ain,
                               const float* __restrict__ b2p,
                               const float* __restrict__ W1,
                               const float* __restrict__ b1,
                               float* __restrict__ U,
                               float* __restrict__ Vv)
{
    __shared__ float ylds[32][CIN];
    const int nbase = blockIdx.x * 32;
    const int tid = threadIdx.x;

    for (int idx = tid; idx < 32 * CIN; idx += COUT) {
        int nn = idx / CIN, k = idx - nn * CIN;
        int n = nbase + nn;
        float val = 0.f;
        if (n < NN) {
            if (FIRST) {
                val = xin[(size_t)n * CIN + k];
            } else {
                float a = ain[(size_t)n * CIN + k];
                val = fmaxf(a + b2p[k], 0.f);   // -inf sentinel -> 0
            }
        }
        ylds[nn][k] = val;
    }
    __syncthreads();

    const int j = tid;
    float ua[32], va[32];
    #pragma unroll
    for (int t = 0; t < 32; ++t) { ua[t] = 0.f; va[t] = 0.f; }

    for (int k4 = 0; k4 < CIN / 4; ++k4) {
        float wd[4], wb[4];
        #pragma unroll
        for (int i = 0; i < 4; ++i) {
            float a = W1[(size_t)(k4 * 4 + i) * COUT + j];
            float b = W1[(size_t)(CIN + k4 * 4 + i) * COUT + j];
            wb[i] = b;
            wd[i] = a - b;
        }
        #pragma unroll
        for (int t = 0; t < 32; ++t) {
            const float4 y4 = *reinterpret_cast<const float4*>(&ylds[t][k4 * 4]);
            ua[t] = fmaf(y4.x, wd[0], ua[t]);
            ua[t] = fmaf(y4.y, wd[1], ua[t]);
            ua[t] = fmaf(y4.z, wd[2], ua[t]);
            ua[t] = fmaf(y4.w, wd[3], ua[t]);
            va[t] = fmaf(y4.x, wb[0], va[t]);
            va[t] = fmaf(y4.y, wb[1], va[t]);
            va[t] = fmaf(y4.z, wb[2], va[t]);
            va[t] = fmaf(y4.w, wb[3], va[t]);
        }
    }

    const float bj = b1[j];
    for (int t = 0; t < 32; ++t) {
        int n = nbase + t;
        if (n < NN) {
            U [(size_t)n * COUT + j] = ua[t] + bj;
            Vv[(size_t)n * COUT + j] = va[t];
        }
    }
}

// ---------------------------------------------------------------------------
// W2 -> MFMA B-fragment prep (hi/lo bf16 split), KS-MAJOR fragment packing:
// frag = ks*NT + nt; lane l holds W2[ks*32 + (l>>4)*8 + m][nt*16 + (l&15)],
// m=0..7, packed at F[(frag*64+lane)*8]. (ks-major so the edge kernel's
// rolled-ks loop reads nt-fragments at constant 1KB offsets.)
// ---------------------------------------------------------------------------
template<int COUT>
__global__ void w2frag_prep(const float* __restrict__ W2,
                            unsigned short* __restrict__ Fhi,
                            unsigned short* __restrict__ Flo)
{
    constexpr int NT = COUT / 16;
    constexpr int KS = COUT / 32;
    int t = blockIdx.x * 256 + threadIdx.x;
    if (t >= NT * KS * 64) return;
    int frag = t >> 6, lane = t & 63;
    int nt = frag % NT, ks = frag / NT;
    int col = nt * 16 + (lane & 15);
    int k0 = ks * 32 + (lane >> 4) * 8;
    size_t base = (size_t)t * 8;
    #pragma unroll
    for (int m = 0; m < 8; ++m) {
        float w = W2[(size_t)(k0 + m) * COUT + col];
        __bf16 hb = (__bf16)w;
        float hf = (float)hb;
        __bf16 lb = (__bf16)(w - hf);
        Fhi[base + m] = __builtin_bit_cast(unsigned short, hb);
        Flo[base + m] = __builtin_bit_cast(unsigned short, lb);
    }
}

// ---------------------------------------------------------------------------
// MFMA edge kernel, direct-gather A, single-pass 16-edge tiles.
// Round-8 scratch fix: NO local arrays in the hot loop, NO pointer-passed
// split helper (rounds 4-7 had `float t8[8]` passed by const float* ->
// GB-scale scratch round-trips). The hi/lo split is named scalars + direct
// constant-index ext_vector element writes. ks loop is ROLLED; only
// statically-indexed acc[NT]/nmax[NT] remain.
// ---------------------------------------------------------------------------
template<int COUT>
__global__ void __launch_bounds__(512, 2) edge_node_mfma(
    const float* __restrict__ U, const float* __restrict__ Vv,
    const int* __restrict__ s_src, const int* __restrict__ row_off,
    const unsigned short* __restrict__ Fhi, const unsigned short* __restrict__ Flo,
    float* __restrict__ agg)
{
    constexpr int KS = COUT / 32;          // MFMA K-steps (4 / 2)
    constexpr int NT = COUT / 16;          // output col tiles (8 / 4)
    constexpr int NFRAG = KS * NT;

    __shared__ __align__(16) unsigned short w2hi[NFRAG * 512];
    __shared__ __align__(16) unsigned short w2lo[NFRAG * 512];
    __shared__ __align__(16) float u_lds[8 * COUT];

    const int tid = threadIdx.x;
    for (int i = tid; i < NFRAG * 64; i += 512) {
        *reinterpret_cast<u16x8*>(&w2hi[i * 8]) =
            *reinterpret_cast<const u16x8*>(&Fhi[(size_t)i * 8]);
        *reinterpret_cast<u16x8*>(&w2lo[i * 8]) =
            *reinterpret_cast<const u16x8*>(&Flo[(size_t)i * 8]);
    }

    const int wave = tid >> 6, lane = tid & 63;
    const int arow = lane & 15;            // A row (edge within pass)
    const int akc  = lane >> 4;            // k-chunk within K-step

    const int n = blockIdx.x * 8 + wave;   // grid = NN/8 exactly
    const int off0 = row_off[n];
    const int deg  = row_off[n + 1] - off0;

    // stage this wave's U row to LDS (broadcast-read later, ~free)
    for (int i = lane; i < COUT; i += 64)
        u_lds[wave * COUT + i] = U[(size_t)n * COUT + i];

    __syncthreads();   // w2 + U ready; no block syncs after this

    float nmax[NT];
    #pragma unroll
    for (int nt = 0; nt < NT; ++nt) nmax[nt] = -INFINITY;

    for (int pb = 0; pb < deg; pb += 16) {
        const bool valid = (pb + arow) < deg;
        const int sv = valid ? s_src[off0 + pb + arow] : 0;
        const float* vrow = &Vv[(size_t)sv * COUT];
        const float vm = valid ? 1.f : 0.f;

        f32x4 acc[NT];
        #pragma unroll
        for (int nt = 0; nt < NT; ++nt) acc[nt] = f32x4{0.f, 0.f, 0.f, 0.f};

        #pragma unroll 1
        for (int ks = 0; ks < KS; ++ks) {
            const int kof = (ks * 4 + akc) * 8;
            const float4 ua4 = *reinterpret_cast<const float4*>(&u_lds[wave * COUT + kof]);
            const float4 ub4 = *reinterpret_cast<const float4*>(&u_lds[wave * COUT + kof + 4]);
            const float4 va4 = *reinterpret_cast<const float4*>(vrow + kof);
            const float4 vb4 = *reinterpret_cast<const float4*>(vrow + kof + 4);

            const float s0 = vm * fmaxf(ua4.x + va4.x, 0.f);
            const float s1 = vm * fmaxf(ua4.y + va4.y, 0.f);
            const float s2 = vm * fmaxf(ua4.z + va4.z, 0.f);
            const float s3 = vm * fmaxf(ua4.w + va4.w, 0.f);
            const float s4 = vm * fmaxf(ub4.x + vb4.x, 0.f);
            const float s5 = vm * fmaxf(ub4.y + vb4.y, 0.f);
            const float s6 = vm * fmaxf(ub4.z + vb4.z, 0.f);
            const float s7 = vm * fmaxf(ub4.w + vb4.w, 0.f);

            bf16x8 ahi, alo;
            {
                __bf16 h;
                h = (__bf16)s0; ahi[0] = h; alo[0] = (__bf16)(s0 - (float)h);
                h = (__bf16)s1; ahi[1] = h; alo[1] = (__bf16)(s1 - (float)h);
                h = (__bf16)s2; ahi[2] = h; alo[2] = (__bf16)(s2 - (float)h);
                h = (__bf16)s3; ahi[3] = h; alo[3] = (__bf16)(s3 - (float)h);
                h = (__bf16)s4; ahi[4] = h; alo[4] = (__bf16)(s4 - (float)h);
                h = (__bf16)s5; ahi[5] = h; alo[5] = (__bf16)(s5 - (float)h);
                h = (__bf16)s6; ahi[6] = h; alo[6] = (__bf16)(s6 - (float)h);
                h = (__bf16)s7; ahi[7] = h; alo[7] = (__bf16)(s7 - (float)h);
            }

            const unsigned short* hbase = &w2hi[(size_t)(ks * NT * 64 + lane) * 8];
            const unsigned short* lbase = &w2lo[(size_t)(ks * NT * 64 + lane) * 8];
            #pragma unroll
            for (int nt = 0; nt < NT; ++nt) {
                bf16x8 bhi = __builtin_bit_cast(bf16x8,
                    *reinterpret_cast<const u16x8*>(hbase + (size_t)nt * 512));
                bf16x8 blo = __builtin_bit_cast(bf16x8,
                    *reinterpret_cast<const u16x8*>(lbase + (size_t)nt * 512));
                acc[nt] = __builtin_amdgcn_mfma_f32_16x16x32_bf16(ahi, bhi, acc[nt], 0, 0, 0);
                acc[nt] = __builtin_amdgcn_mfma_f32_16x16x32_bf16(ahi, blo, acc[nt], 0, 0, 0);
                acc[nt] = __builtin_amdgcn_mfma_f32_16x16x32_bf16(alo, bhi, acc[nt], 0, 0, 0);
            }
        }

        // masked max (D: row = akc*4 + r, col = nt*16 + (lane&15))
        #pragma unroll
        for (int nt = 0; nt < NT; ++nt) {
            float m4 = -INFINITY;
            if (pb + akc * 4 + 0 < deg) m4 = fmaxf(m4, acc[nt][0]);
            if (pb + akc * 4 + 1 < deg) m4 = fmaxf(m4, acc[nt][1]);
            if (pb + akc * 4 + 2 < deg) m4 = fmaxf(m4, acc[nt][2]);
            if (pb + akc * 4 + 3 < deg) m4 = fmaxf(m4, acc[nt][3]);
            m4 = fmaxf(m4, __shfl_xor(m4, 16, 64));
            m4 = fmaxf(m4, __shfl_xor(m4, 32, 64));
            nmax[nt] = fmaxf(nmax[nt], m4);
        }
    }

    // direct store; deg==0 leaves -inf sentinel
    if (lane < 16) {
        #pragma unroll
        for (int nt = 0; nt < NT; ++nt)
            agg[(size_t)n * COUT + nt * 16 + lane] = nmax[nt];
    }
}

__global__ void finalize_k(const float* __restrict__ agg,
                           const float* __restrict__ b2,
                           float* __restrict__ out) {
    int i = blockIdx.x * 256 + threadIdx.x;
    if (i < NN * 128) {
        float a = agg[i];
        out[i] = (a == -INFINITY) ? 0.f : a + b2[i & 127];
    }
}

// ---------------------------------------------------------------------------
extern "C" void kernel_launch(void* const* d_in, const int* in_sizes, int n_in,
                              void* d_out, int out_size, void* d_ws, size_t ws_size,
                              hipStream_t stream)
{
    const float* x  = (const float*)d_in[0];
    const int*   ei = (const int*)d_in[1];
    const int* src = ei;          // edge_index[0]
    const int* dst = ei + NE;     // edge_index[1]

    const float *W1[4], *B1[4], *W2[4], *B2[4];
    for (int i = 0; i < 4; ++i) {
        W1[i] = (const float*)d_in[2 + 4 * i];
        B1[i] = (const float*)d_in[3 + 4 * i];
        W2[i] = (const float*)d_in[4 + 4 * i];
        B2[i] = (const float*)d_in[5 + 4 * i];
    }

    float* U   = (float*)d_ws;
    float* V   = U   + (size_t)NN * 128;
    float* agg = V   + (size_t)NN * 128;
    int* row_off = (int*)(agg + (size_t)NN * 128);   // NN+16 ints (padded)
    int* cnt     = row_off + (NN + 16);              // NN+16 ints
    int* s_src   = cnt + (NN + 16);                  // NE ints
    unsigned short* fbase = (unsigned short*)(s_src + NE);
    unsigned short *FH[4], *FL[4];
    for (int i = 0; i < 4; ++i) {
        FH[i] = fbase + (size_t)i * 32768;
        FL[i] = FH[i] + 16384;
    }

    float* out = (float*)d_out;

    // ---- one-time CSR build ----
    (void)hipMemsetAsync(cnt, 0, (size_t)NN * sizeof(int), stream);
    hipLaunchKernelGGL(hist_k, dim3((NE + 255) / 256), dim3(256), 0, stream, dst, cnt);
    hipLaunchKernelGGL(scan_k, dim3(1), dim3(1024), 0, stream, cnt, row_off);
    hipLaunchKernelGGL(copy_k, dim3((NN + 255) / 256), dim3(256), 0, stream, row_off, cnt, NN);
    hipLaunchKernelGGL(scatter_k, dim3((NE + 255) / 256), dim3(256), 0, stream, src, dst, cnt, s_src);

    // ---- W2 fragment prep (hi/lo bf16 split, ks-major), all 4 layers ----
    hipLaunchKernelGGL((w2frag_prep<64>),  dim3(2), dim3(256), 0, stream, W2[0], FH[0], FL[0]);
    hipLaunchKernelGGL((w2frag_prep<128>), dim3(8), dim3(256), 0, stream, W2[1], FH[1], FL[1]);
    hipLaunchKernelGGL((w2frag_prep<128>), dim3(8), dim3(256), 0, stream, W2[2], FH[2], FL[2]);
    hipLaunchKernelGGL((w2frag_prep<128>), dim3(8), dim3(256), 0, stream, W2[3], FH[3], FL[3]);

    const int nblkA = (NN + 31) / 32;
    const int nblkE = NN / 8;      // 6250

    // ---- layer 0: 32 -> 64 ----
    hipLaunchKernelGGL((node_transform<32, 64, true>), dim3(nblkA), dim3(64), 0, stream,
                       x, nullptr, nullptr, W1[0], B1[0], U, V);
    hipLaunchKernelGGL((edge_node_mfma<64>), dim3(nblkE), dim3(512), 0, stream,
                       U, V, s_src, row_off, FH[0], FL[0], agg);

    // ---- layer 1: 64 -> 128 ----
    hipLaunchKernelGGL((node_transform<64, 128, false>), dim3(nblkA), dim3(128), 0, stream,
                       nullptr, agg, B2[0], W1[1], B1[1], U, V);
    hipLaunchKernelGGL((edge_node_mfma<128>), dim3(nblkE), dim3(512), 0, stream,
                       U, V, s_src, row_off, FH[1], FL[1], agg);

    // ---- layer 2: 128 -> 128 ----
    hipLaunchKernelGGL((node_transform<128, 128, false>), dim3(nblkA), dim3(128), 0, stream,
                       nullptr, agg, B2[1], W1[2], B1[2], U, V);
    hipLaunchKernelGGL((edge_node_mfma<128>), dim3(nblkE), dim3(512), 0, stream,
                       U, V, s_src, row_off, FH[2], FL[2], agg);

    // ---- layer 3: 128 -> 128 ----
    hipLaunchKernelGGL((node_transform<128, 128, false>), dim3(nblkA), dim3(128), 0, stream,
                       nullptr, agg, B2[2], W1[3], B1[3], U, V);
    hipLaunchKernelGGL((edge_node_mfma<128>), dim3(nblkE), dim3(512), 0, stream,
                       U, V, s_src, row_off, FH[3], FL[3], agg);

    // ---- finalize: +b2_3, empty -> 0 ----
    hipLaunchKernelGGL(finalize_k, dim3((NN * 128 + 255) / 256), dim3(256), 0, stream,
                       agg, B2[3], out);
}